// Round 1
// baseline (16.073 us; speedup 1.0000x reference)
//
#include <hip/hip_runtime.h>
#include <hip/hip_bf16.h>

// Span-mean aggregation:
//   out[b,s,:] = (s < lengths[b]) ? mean(x[b, start..end), :]) : 0
// B=8, T=4096, S=512, D=768 in the reference; sizes derived at launch.
//
// One block per (b,s). blockDim = D/4 lanes rounded to a wave multiple;
// each thread owns one float4 column slice, sums n<=8 rows, scales, stores.

__global__ void span_mean_kernel(const float4* __restrict__ x,
                                 const int* __restrict__ lengths,
                                 const int* __restrict__ spans,
                                 float4* __restrict__ out,
                                 int S, int T, int D4) {
    const int bs = blockIdx.x;          // b * S + s
    const int b  = bs / S;
    const int s  = bs - b * S;

    float4* __restrict__ o = out + (size_t)bs * D4;

    if (s >= lengths[b]) {
        // Invalid span: write zeros, skip input entirely.
        const float4 z = make_float4(0.f, 0.f, 0.f, 0.f);
        for (int d = threadIdx.x; d < D4; d += blockDim.x) o[d] = z;
        return;
    }

    const int i0 = spans[2 * bs + 0];
    const int j0 = spans[2 * bs + 1];
    const int n  = j0 - i0;
    const float inv = 1.0f / (float)(n > 1 ? n : 1);

    const float4* __restrict__ base = x + ((size_t)b * T + i0) * (size_t)D4;

    for (int d = threadIdx.x; d < D4; d += blockDim.x) {
        float4 acc = make_float4(0.f, 0.f, 0.f, 0.f);
        const float4* p = base + d;
        #pragma unroll 8
        for (int k = 0; k < n; ++k) {
            float4 v = p[(size_t)k * D4];
            acc.x += v.x; acc.y += v.y; acc.z += v.z; acc.w += v.w;
        }
        o[d] = make_float4(acc.x * inv, acc.y * inv, acc.z * inv, acc.w * inv);
    }
}

extern "C" void kernel_launch(void* const* d_in, const int* in_sizes, int n_in,
                              void* d_out, int out_size, void* d_ws, size_t ws_size,
                              hipStream_t stream) {
    const float* x        = (const float*)d_in[0];   // (B, T, D) fp32
    const int*   lengths  = (const int*)d_in[1];     // (B,)
    const int*   spans    = (const int*)d_in[2];     // (B, S, 2)
    float*       out      = (float*)d_out;           // (B, S, D) fp32

    const int B  = in_sizes[1];
    const int S  = in_sizes[2] / (2 * B);
    const int D  = out_size / (B * S);
    const int T  = in_sizes[0] / (B * D);
    const int D4 = D / 4;                            // D=768 -> 192

    // Block size: cover D4 lanes with whole waves, cap at 256.
    int block = ((D4 + 63) / 64) * 64;
    if (block > 256) block = 256;
    if (block < 64)  block = 64;

    dim3 grid(B * S);
    span_mean_kernel<<<grid, dim3(block), 0, stream>>>(
        (const float4*)x, lengths, spans, (float4*)out, S, T, D4);
}